// Round 10
// baseline (150.354 us; speedup 1.0000x reference)
//
#include <hip/hip_runtime.h>

#define N_NODES 40000
#define N_EDGES 640000
#define D_FEAT  128
#define CAP     32        // 32 packed 4B entries per node = one 128B line
#define OCAP    8192      // overflow list capacity (expected ~6 entries used)
#define CSTRIDE 32        // cursor stride in ints: 1 cursor per 128B line
#define SCAT_BLOCKS 2500  // 2500*256 = 640000 = N_EDGES (1 edge/thread)
#define CONV_BLOCKS 5000  // 5000*256 threads * 4 floats = 5.12M = N_NODES*D_FEAT
#define SCAN_BLOCK 256
#define N_SCAN_BLOCKS ((N_NODES + SCAN_BLOCK - 1) / SCAN_BLOCK)   // 157

typedef float    f32x4 __attribute__((ext_vector_type(4)));   // native vectors for
typedef unsigned u32x4 __attribute__((ext_vector_type(4)));   // nontemporal builtins

__device__ __forceinline__ unsigned bf16r(float f) {   // round-to-nearest-even bf16 bits
    unsigned u = __float_as_uint(f);
    return (u + 0x7FFFu + ((u >> 16) & 1u)) >> 16;
}

// ================= Fast path: fused scatter+convert, then bf16 gather ========
// cursors are padded to one per 128B cache line (CSTRIDE) so each line sees
// ~16 atomics instead of 256 — attacks per-line atomic serialization.
// ocount lives in cursors[1] (node 0's padding) so one memset covers both.

__global__ __launch_bounds__(256) void prep_kernel(
    const float* __restrict__ x,
    const int*   __restrict__ rows,
    const int*   __restrict__ cols,
    const float* __restrict__ vals,
    int*          __restrict__ cursors,   // zeroed, [N_NODES*CSTRIDE]
    unsigned*     __restrict__ bucket,    // [N_NODES*CAP] packed (col<<16|bf16)
    int2*         __restrict__ overflow,  // [OCAP] (row, packed)
    uint2*        __restrict__ xbf)       // [N_NODES*32] = bf16 rows, 256B each
{
    int b = blockIdx.x;
    if (b < SCAT_BLOCKS) {
        int e = b * 256 + threadIdx.x;                   // < 640,000 exactly
        int   r = rows[e];
        int   c = cols[e];
        float v = vals[e];
        unsigned p = ((unsigned)c << 16) | bf16r(v);
        int slot = atomicAdd(&cursors[(size_t)r * CSTRIDE], 1);
        if (slot < CAP) bucket[(size_t)r * CAP + slot] = p;
        else { int o = atomicAdd(&cursors[1], 1); if (o < OCAP) overflow[o] = make_int2(r, (int)p); }
        return;
    }
    int idx = (b - SCAT_BLOCKS) * 256 + threadIdx.x;     // < 1,280,000 exactly
    float4 f = ((const float4*)x)[idx];
    uint2 o;
    o.x = bf16r(f.x) | (bf16r(f.y) << 16);
    o.y = bf16r(f.z) | (bf16r(f.w) << 16);
    xbf[idx] = o;
}

// One half-wave (32 lanes) per node; entries 4B packed, x rows bf16 (8B/lane).
// Streaming data (bucket in, out stores) is nontemporal to keep L2 for xbf.
__global__ __launch_bounds__(256) void gather_bf_kernel(
    const uint2*    __restrict__ xbf,
    const int*      __restrict__ cursors,
    const unsigned* __restrict__ bucket,
    const int2*     __restrict__ overflow,
    const float*    __restrict__ bias,
    float*          __restrict__ out)
{
    int t    = blockIdx.x * blockDim.x + threadIdx.x;
    int node = t >> 5;
    if (node >= N_NODES) return;
    int lane = t & 31;

    int k = min(cursors[(size_t)node * CSTRIDE], CAP);
    const unsigned* base = bucket + (size_t)node * CAP;

    float4 acc0 = make_float4(0.f, 0.f, 0.f, 0.f);
    float4 acc1 = make_float4(0.f, 0.f, 0.f, 0.f);
    float  deg  = 0.f;

    #define PROC(entry, acc)  {                                            \
        unsigned _en = (entry);                                            \
        float _v = __uint_as_float(_en << 16);                             \
        unsigned _c = _en >> 16;                                           \
        uint2 _w = xbf[(size_t)_c * 32 + lane];                            \
        float _f0 = __uint_as_float(_w.x << 16);                           \
        float _f1 = __uint_as_float(_w.x & 0xFFFF0000u);                   \
        float _f2 = __uint_as_float(_w.y << 16);                           \
        float _f3 = __uint_as_float(_w.y & 0xFFFF0000u);                   \
        deg += _v;                                                         \
        acc.x += _v * _f0; acc.y += _v * _f1;                              \
        acc.z += _v * _f2; acc.w += _v * _f3; }

    int e = 0;
    for (; e + 4 <= k; e += 4) {
        u32x4 p = __builtin_nontemporal_load((const u32x4*)(base + e));
        PROC(p.x, acc0); PROC(p.y, acc1); PROC(p.z, acc0); PROC(p.w, acc1);
    }
    for (; e < k; ++e) PROC(base[e], acc0);

    // Rare overflow entries (count in cursors[1]; 0 in the common case).
    int oc = min(cursors[1] - (cursors[0] > CAP ? 0 : 0), OCAP);  // cursors[1] is ocount
    oc = min(cursors[1], OCAP);
    for (int i = 0; i < oc; ++i) {
        int2 ent = overflow[i];
        if (ent.x == node) PROC((unsigned)ent.y, acc0);
    }
    #undef PROC

    float inv = (deg == 0.f) ? 0.f : 1.f / deg;
    float4 bv = ((const float4*)bias)[lane];
    f32x4 ov;
    ov.x = (acc0.x + acc1.x) * inv + bv.x;
    ov.y = (acc0.y + acc1.y) * inv + bv.y;
    ov.z = (acc0.z + acc1.z) * inv + bv.z;
    ov.w = (acc0.w + acc1.w) * inv + bv.w;
    __builtin_nontemporal_store(ov, (f32x4*)(out + (size_t)node * D_FEAT) + lane);
}

// ================= CSR middle path (general fallback, f32) =================

__global__ __launch_bounds__(256) void histogram_kernel(
    const int* __restrict__ rows, int* __restrict__ counts)
{
    int e = blockIdx.x * blockDim.x + threadIdx.x;
    if (e < N_EDGES) atomicAdd(&counts[rows[e]], 1);
}

__global__ __launch_bounds__(SCAN_BLOCK) void scan1_kernel(
    const int* __restrict__ counts, int* __restrict__ offsets, int* __restrict__ blocksums)
{
    __shared__ int tmp[SCAN_BLOCK];
    int t = threadIdx.x;
    int g = blockIdx.x * SCAN_BLOCK + t;
    int v = (g < N_NODES) ? counts[g] : 0;
    tmp[t] = v;
    __syncthreads();
    #pragma unroll
    for (int off = 1; off < SCAN_BLOCK; off <<= 1) {
        int add = (t >= off) ? tmp[t - off] : 0;
        __syncthreads();
        tmp[t] += add;
        __syncthreads();
    }
    if (g < N_NODES) offsets[g] = tmp[t] - v;
    if (t == SCAN_BLOCK - 1) blocksums[blockIdx.x] = tmp[t];
}

__global__ __launch_bounds__(SCAN_BLOCK) void scan2_kernel(int* __restrict__ blocksums)
{
    __shared__ int tmp[SCAN_BLOCK];
    int t = threadIdx.x;
    int v = (t < N_SCAN_BLOCKS) ? blocksums[t] : 0;
    tmp[t] = v;
    __syncthreads();
    #pragma unroll
    for (int off = 1; off < SCAN_BLOCK; off <<= 1) {
        int add = (t >= off) ? tmp[t - off] : 0;
        __syncthreads();
        tmp[t] += add;
        __syncthreads();
    }
    if (t < N_SCAN_BLOCKS) blocksums[t] = tmp[t] - v;
}

__global__ __launch_bounds__(SCAN_BLOCK) void scan3_kernel(
    int* __restrict__ offsets, int* __restrict__ cursors, const int* __restrict__ blocksums)
{
    int t = threadIdx.x;
    int g = blockIdx.x * SCAN_BLOCK + t;
    if (g < N_NODES) {
        int o = offsets[g] + blocksums[blockIdx.x];
        offsets[g] = o;
        cursors[g] = o;
    }
    if (g == 0) offsets[N_NODES] = N_EDGES;
}

__global__ __launch_bounds__(256) void bucket_kernel(
    const int* __restrict__ rows, const int* __restrict__ cols,
    const float* __restrict__ vals, int* __restrict__ cursors, int2* __restrict__ bucket)
{
    int e = blockIdx.x * blockDim.x + threadIdx.x;
    if (e >= N_EDGES) return;
    int r = rows[e];
    int pos = atomicAdd(&cursors[r], 1);
    bucket[pos] = make_int2(cols[e], __float_as_int(vals[e]));
}

__global__ __launch_bounds__(256) void gather_csr_kernel(
    const float* __restrict__ x, const int* __restrict__ offsets,
    const int2* __restrict__ bucket, const float* __restrict__ bias,
    float* __restrict__ out)
{
    int t = blockIdx.x * blockDim.x + threadIdx.x;
    int node = t >> 5;
    if (node >= N_NODES) return;
    int lane = t & 31;
    int beg = offsets[node];
    int end = offsets[node + 1];
    float4 acc = make_float4(0.f, 0.f, 0.f, 0.f);
    float deg = 0.f;
    int2 ent = (beg < end) ? bucket[beg] : make_int2(0, 0);
    for (int e = beg; e < end; ++e) {
        int2 cur = ent;
        if (e + 1 < end) ent = bucket[e + 1];
        float v = __int_as_float(cur.y);
        deg += v;
        float4 xv = ((const float4*)(x + (size_t)cur.x * D_FEAT))[lane];
        acc.x += v * xv.x; acc.y += v * xv.y; acc.z += v * xv.z; acc.w += v * xv.w;
    }
    float inv = (deg == 0.f) ? 0.f : 1.f / deg;
    float4 bv = ((const float4*)bias)[lane];
    float4 ov;
    ov.x = acc.x * inv + bv.x; ov.y = acc.y * inv + bv.y;
    ov.z = acc.z * inv + bv.z; ov.w = acc.w * inv + bv.w;
    ((float4*)(out + (size_t)node * D_FEAT))[lane] = ov;
}

// ================= Atomic fallback =================

__global__ __launch_bounds__(256) void edge_scatter_kernel(
    const float* __restrict__ x, const int* __restrict__ rows,
    const int* __restrict__ cols, const float* __restrict__ vals,
    float* __restrict__ agg, float* __restrict__ deg)
{
    int t = blockIdx.x * blockDim.x + threadIdx.x;
    int edge = t >> 5;
    if (edge >= N_EDGES) return;
    int lane = t & 31;
    int row = rows[edge]; int col = cols[edge]; float v = vals[edge];
    float4 xv = ((const float4*)(x + (size_t)col * D_FEAT))[lane];
    float* dst = agg + (size_t)row * D_FEAT + lane * 4;
    unsafeAtomicAdd(dst + 0, v * xv.x);
    unsafeAtomicAdd(dst + 1, v * xv.y);
    unsafeAtomicAdd(dst + 2, v * xv.z);
    unsafeAtomicAdd(dst + 3, v * xv.w);
    if (lane == 0) unsafeAtomicAdd(deg + row, v);
}

__global__ __launch_bounds__(256) void finalize_kernel(
    float* __restrict__ out, const float* __restrict__ deg, const float* __restrict__ bias)
{
    int t = blockIdx.x * blockDim.x + threadIdx.x;
    int node = t >> 5;
    if (node >= N_NODES) return;
    int lane = t & 31;
    float d = deg[node];
    float inv = (d == 0.f) ? 0.f : 1.f / d;
    float4* o = (float4*)(out + (size_t)node * D_FEAT) + lane;
    float4 bv = ((const float4*)bias)[lane];
    float4 ov = *o;
    ov.x = ov.x * inv + bv.x; ov.y = ov.y * inv + bv.y;
    ov.z = ov.z * inv + bv.z; ov.w = ov.w * inv + bv.w;
    *o = ov;
}

// ================= launch =================

extern "C" void kernel_launch(void* const* d_in, const int* in_sizes, int n_in,
                              void* d_out, int out_size, void* d_ws, size_t ws_size,
                              hipStream_t stream) {
    const float* x    = (const float*)d_in[0];
    const int*   rows = (const int*)  d_in[1];
    const int*   cols = (const int*)  d_in[2];
    const float* vals = (const float*)d_in[3];
    const float* bias = (const float*)d_in[4];
    float* out = (float*)d_out;

    // Fast-path layout (bytes):
    //   cursors  @ 0          (N_NODES*CSTRIDE*4 = 5,120,000; ocount = cursors[1])
    //   overflow @ 5,120,000  (OCAP * 8 = 65,536)
    //   x_bf     @ 5,185,536  (N_NODES*D_FEAT*2 = 10,240,000)
    //   bucket   @ 15,425,536 (N_NODES*CAP*4 = 5,120,000)  [128B aligned]
    char* wb = (char*)d_ws;
    int*      f_cursors  = (int*)     wb;
    int2*     f_overflow = (int2*)   (wb + 5120000);
    uint2*    f_xbf      = (uint2*)  (wb + 5185536);
    unsigned* f_bucket   = (unsigned*)(wb + 15425536);
    size_t need_fast = 15425536 + (size_t)N_NODES * CAP * 4;   // ~20.5 MB

    // CSR-path layout (ints): counts | offsets@40064 | cursors@80128 | blocksums@120128 | bucket@120448
    int* w = (int*)d_ws;
    size_t need_csr = ((size_t)120448 + 2u * N_EDGES) * sizeof(int);   // ~5.6 MB

    if (ws_size >= need_fast) {
        (void)hipMemsetAsync(f_cursors, 0, (size_t)N_NODES * CSTRIDE * 4, stream);
        prep_kernel<<<SCAT_BLOCKS + CONV_BLOCKS, 256, 0, stream>>>(
            x, rows, cols, vals, f_cursors, f_bucket, f_overflow, f_xbf);
        int threads = N_NODES * 32;
        gather_bf_kernel<<<(threads + 255) / 256, 256, 0, stream>>>(
            f_xbf, f_cursors, f_bucket, f_overflow, bias, out);
    } else if (ws_size >= need_csr) {
        int*  counts    = w;
        int*  offsets   = w + 40064;
        int*  cursors   = w + 80128;
        int*  blocksums = w + 120128;
        int2* bucket    = (int2*)(w + 120448);
        (void)hipMemsetAsync(counts, 0, N_NODES * sizeof(int), stream);
        histogram_kernel<<<(N_EDGES + 255) / 256, 256, 0, stream>>>(rows, counts);
        scan1_kernel<<<N_SCAN_BLOCKS, SCAN_BLOCK, 0, stream>>>(counts, offsets, blocksums);
        scan2_kernel<<<1, SCAN_BLOCK, 0, stream>>>(blocksums);
        scan3_kernel<<<N_SCAN_BLOCKS, SCAN_BLOCK, 0, stream>>>(offsets, cursors, blocksums);
        bucket_kernel<<<(N_EDGES + 255) / 256, 256, 0, stream>>>(rows, cols, vals, cursors, bucket);
        int threads = N_NODES * 32;
        gather_csr_kernel<<<(threads + 255) / 256, 256, 0, stream>>>(x, offsets, bucket, bias, out);
    } else {
        float* deg = (float*)d_ws;
        (void)hipMemsetAsync(out, 0, (size_t)N_NODES * D_FEAT * sizeof(float), stream);
        (void)hipMemsetAsync(deg, 0, (size_t)N_NODES * sizeof(float), stream);
        int et = N_EDGES * 32;
        edge_scatter_kernel<<<(et + 255) / 256, 256, 0, stream>>>(x, rows, cols, vals, out, deg);
        int nt = N_NODES * 32;
        finalize_kernel<<<(nt + 255) / 256, 256, 0, stream>>>(out, deg, bias);
    }
}

// Round 11
// 133.112 us; speedup vs baseline: 1.1295x; 1.1295x over previous
//
#include <hip/hip_runtime.h>

#define N_NODES 40000
#define N_EDGES 640000
#define D_FEAT  128
#define CAP     32        // 32 packed 4B entries per node = one 128B line
#define OCAP    8192      // overflow list capacity (expected ~6 entries used)
#define NSLICE  8         // row slices == XCD count
#define SLICE_NODES 5000  // N_NODES / NSLICE
#define GROUPS  250       // edge chunks
#define CHUNK   2560      // edges per chunk (GROUPS*CHUNK == N_EDGES)
#define EPT     10        // CHUNK / 256 edges per thread
#define SCAT_BLOCKS (GROUPS * NSLICE)   // 2000
#define CONV_BLOCKS 5000  // 5000*256 threads * 4 floats = 5.12M = N_NODES*D_FEAT
#define SCAN_BLOCK 256
#define N_SCAN_BLOCKS ((N_NODES + SCAN_BLOCK - 1) / SCAN_BLOCK)   // 157

typedef float    f32x4 __attribute__((ext_vector_type(4)));
typedef unsigned u32x4 __attribute__((ext_vector_type(4)));

__device__ __forceinline__ unsigned bf16r(float f) {   // round-to-nearest-even bf16 bits
    unsigned u = __float_as_uint(f);
    return (u + 0x7FFFu + ((u >> 16) & 1u)) >> 16;
}

// ================= Fast path =================
// Scatter is XCD-partitioned: block b (XCD b%8 under round-robin dispatch)
// processes only rows in its slice, so bucket/cursor lines stay in one L2.
// ocount = cursors[N_NODES].

__global__ __launch_bounds__(256) void prep_kernel(
    const float* __restrict__ x,
    const int*   __restrict__ rows,
    const int*   __restrict__ cols,
    const float* __restrict__ vals,
    int*          __restrict__ cursors,   // zeroed, N_NODES+1 ints
    unsigned*     __restrict__ bucket,    // [N_NODES*CAP] packed (col<<16|bf16)
    int2*         __restrict__ overflow,  // [OCAP] (row, packed)
    uint2*        __restrict__ xbf)       // [N_NODES*32] = bf16 rows, 256B each
{
    int b = blockIdx.x;
    if (b < SCAT_BLOCKS) {
        int grp  = b >> 3;              // edge chunk 0..249
        int sl   = b & 7;               // row slice == XCD (heuristic)
        int base = grp * CHUNK;
        int rlo  = sl * SLICE_NODES;
        int rhi  = rlo + SLICE_NODES;
        #pragma unroll
        for (int i = 0; i < EPT; ++i) {
            int e = base + i * 256 + threadIdx.x;   // coalesced
            int r = rows[e];
            if (r >= rlo && r < rhi) {
                unsigned p = ((unsigned)cols[e] << 16) | bf16r(vals[e]);
                int slot = atomicAdd(&cursors[r], 1);
                if (slot < CAP) bucket[(size_t)r * CAP + slot] = p;
                else { int o = atomicAdd(&cursors[N_NODES], 1);
                       if (o < OCAP) overflow[o] = make_int2(r, (int)p); }
            }
        }
        return;
    }
    int idx = (b - SCAT_BLOCKS) * 256 + threadIdx.x;   // < 1,280,000 exactly
    float4 f = ((const float4*)x)[idx];
    uint2 o;
    o.x = bf16r(f.x) | (bf16r(f.y) << 16);
    o.y = bf16r(f.z) | (bf16r(f.w) << 16);
    xbf[idx] = o;
}

// Gather: one half-wave per node; nodes remapped so the node's bucket slice is
// XCD-local. Entries loaded one-per-lane (coalesced 128B), bitonic-sorted by
// packed value (col in high bits) so ALL waves sweep xbf low->high in near
// lockstep -> per-XCD L2 working set ~1-2MB instead of 10.2MB.
__global__ __launch_bounds__(256) void gather_bf_kernel(
    const uint2*    __restrict__ xbf,
    const int*      __restrict__ cursors,
    const unsigned* __restrict__ bucket,
    const int2*     __restrict__ overflow,
    const float*    __restrict__ bias,
    float*          __restrict__ out)
{
    int b    = blockIdx.x;            // 5000 blocks
    int hw   = threadIdx.x >> 5;      // 0..7
    int lane = threadIdx.x & 31;
    int node = (b & 7) * SLICE_NODES + (b >> 3) * 8 + hw;   // XCD-local slice

    int k = min(cursors[node], CAP);
    const unsigned* base = bucket + (size_t)node * CAP;

    // one entry per lane (single coalesced 128B line), pad with 0xFFFFFFFF
    unsigned ent = (lane < k) ? base[lane] : 0xFFFFFFFFu;

    // bitonic sort ascending across the 32-lane half-wave (xor masks <= 16
    // stay within the half). col<40000 => valid entries < 0x9C40FFFF < pad.
    #pragma unroll
    for (int kk = 2; kk <= 32; kk <<= 1) {
        #pragma unroll
        for (int j = kk >> 1; j > 0; j >>= 1) {
            unsigned other = __shfl_xor(ent, j, 64);
            bool up      = ((lane & kk) == 0);
            bool lower   = ((lane & j) == 0);
            unsigned mn  = min(ent, other), mx = max(ent, other);
            ent = (up == lower) ? mn : mx;
        }
    }

    int wb = threadIdx.x & 32;        // shfl base of my half-wave

    float4 acc0 = make_float4(0.f, 0.f, 0.f, 0.f);
    float4 acc1 = make_float4(0.f, 0.f, 0.f, 0.f);
    float  deg  = 0.f;

    #define PROC(entry, acc)  {                                            \
        unsigned _en = (entry);                                            \
        float _v = __uint_as_float(_en << 16);                             \
        unsigned _c = _en >> 16;                                           \
        uint2 _w = xbf[(size_t)_c * 32 + lane];                            \
        float _f0 = __uint_as_float(_w.x << 16);                           \
        float _f1 = __uint_as_float(_w.x & 0xFFFF0000u);                   \
        float _f2 = __uint_as_float(_w.y << 16);                           \
        float _f3 = __uint_as_float(_w.y & 0xFFFF0000u);                   \
        deg += _v;                                                         \
        acc.x += _v * _f0; acc.y += _v * _f1;                              \
        acc.z += _v * _f2; acc.w += _v * _f3; }

    int e = 0;
    for (; e + 4 <= k; e += 4) {      // ascending-col order, 4 gathers in flight
        unsigned p0 = __shfl(ent, wb + e,     64);
        unsigned p1 = __shfl(ent, wb + e + 1, 64);
        unsigned p2 = __shfl(ent, wb + e + 2, 64);
        unsigned p3 = __shfl(ent, wb + e + 3, 64);
        PROC(p0, acc0); PROC(p1, acc1); PROC(p2, acc0); PROC(p3, acc1);
    }
    for (; e < k; ++e) {
        unsigned p = __shfl(ent, wb + e, 64);
        PROC(p, acc0);
    }

    // Rare overflow entries (ocount==0 in the common case).
    int oc = min(cursors[N_NODES], OCAP);
    for (int i = 0; i < oc; ++i) {
        int2 entv = overflow[i];
        if (entv.x == node) PROC((unsigned)entv.y, acc0);
    }
    #undef PROC

    float inv = (deg == 0.f) ? 0.f : 1.f / deg;
    float4 bv = ((const float4*)bias)[lane];
    f32x4 ov;
    ov.x = (acc0.x + acc1.x) * inv + bv.x;
    ov.y = (acc0.y + acc1.y) * inv + bv.y;
    ov.z = (acc0.z + acc1.z) * inv + bv.z;
    ov.w = (acc0.w + acc1.w) * inv + bv.w;
    __builtin_nontemporal_store(ov, (f32x4*)(out + (size_t)node * D_FEAT) + lane);
}

// ================= CSR middle path (general fallback, f32) =================

__global__ __launch_bounds__(256) void histogram_kernel(
    const int* __restrict__ rows, int* __restrict__ counts)
{
    int e = blockIdx.x * blockDim.x + threadIdx.x;
    if (e < N_EDGES) atomicAdd(&counts[rows[e]], 1);
}

__global__ __launch_bounds__(SCAN_BLOCK) void scan1_kernel(
    const int* __restrict__ counts, int* __restrict__ offsets, int* __restrict__ blocksums)
{
    __shared__ int tmp[SCAN_BLOCK];
    int t = threadIdx.x;
    int g = blockIdx.x * SCAN_BLOCK + t;
    int v = (g < N_NODES) ? counts[g] : 0;
    tmp[t] = v;
    __syncthreads();
    #pragma unroll
    for (int off = 1; off < SCAN_BLOCK; off <<= 1) {
        int add = (t >= off) ? tmp[t - off] : 0;
        __syncthreads();
        tmp[t] += add;
        __syncthreads();
    }
    if (g < N_NODES) offsets[g] = tmp[t] - v;
    if (t == SCAN_BLOCK - 1) blocksums[blockIdx.x] = tmp[t];
}

__global__ __launch_bounds__(SCAN_BLOCK) void scan2_kernel(int* __restrict__ blocksums)
{
    __shared__ int tmp[SCAN_BLOCK];
    int t = threadIdx.x;
    int v = (t < N_SCAN_BLOCKS) ? blocksums[t] : 0;
    tmp[t] = v;
    __syncthreads();
    #pragma unroll
    for (int off = 1; off < SCAN_BLOCK; off <<= 1) {
        int add = (t >= off) ? tmp[t - off] : 0;
        __syncthreads();
        tmp[t] += add;
        __syncthreads();
    }
    if (t < N_SCAN_BLOCKS) blocksums[t] = tmp[t] - v;
}

__global__ __launch_bounds__(SCAN_BLOCK) void scan3_kernel(
    int* __restrict__ offsets, int* __restrict__ cursors, const int* __restrict__ blocksums)
{
    int t = threadIdx.x;
    int g = blockIdx.x * SCAN_BLOCK + t;
    if (g < N_NODES) {
        int o = offsets[g] + blocksums[blockIdx.x];
        offsets[g] = o;
        cursors[g] = o;
    }
    if (g == 0) offsets[N_NODES] = N_EDGES;
}

__global__ __launch_bounds__(256) void bucket_kernel(
    const int* __restrict__ rows, const int* __restrict__ cols,
    const float* __restrict__ vals, int* __restrict__ cursors, int2* __restrict__ bucket)
{
    int e = blockIdx.x * blockDim.x + threadIdx.x;
    if (e >= N_EDGES) return;
    int r = rows[e];
    int pos = atomicAdd(&cursors[r], 1);
    bucket[pos] = make_int2(cols[e], __float_as_int(vals[e]));
}

__global__ __launch_bounds__(256) void gather_csr_kernel(
    const float* __restrict__ x, const int* __restrict__ offsets,
    const int2* __restrict__ bucket, const float* __restrict__ bias,
    float* __restrict__ out)
{
    int t = blockIdx.x * blockDim.x + threadIdx.x;
    int node = t >> 5;
    if (node >= N_NODES) return;
    int lane = t & 31;
    int beg = offsets[node];
    int end = offsets[node + 1];
    float4 acc = make_float4(0.f, 0.f, 0.f, 0.f);
    float deg = 0.f;
    int2 ent = (beg < end) ? bucket[beg] : make_int2(0, 0);
    for (int e = beg; e < end; ++e) {
        int2 cur = ent;
        if (e + 1 < end) ent = bucket[e + 1];
        float v = __int_as_float(cur.y);
        deg += v;
        float4 xv = ((const float4*)(x + (size_t)cur.x * D_FEAT))[lane];
        acc.x += v * xv.x; acc.y += v * xv.y; acc.z += v * xv.z; acc.w += v * xv.w;
    }
    float inv = (deg == 0.f) ? 0.f : 1.f / deg;
    float4 bv = ((const float4*)bias)[lane];
    float4 ov;
    ov.x = acc.x * inv + bv.x; ov.y = acc.y * inv + bv.y;
    ov.z = acc.z * inv + bv.z; ov.w = acc.w * inv + bv.w;
    ((float4*)(out + (size_t)node * D_FEAT))[lane] = ov;
}

// ================= Atomic fallback =================

__global__ __launch_bounds__(256) void edge_scatter_kernel(
    const float* __restrict__ x, const int* __restrict__ rows,
    const int* __restrict__ cols, const float* __restrict__ vals,
    float* __restrict__ agg, float* __restrict__ deg)
{
    int t = blockIdx.x * blockDim.x + threadIdx.x;
    int edge = t >> 5;
    if (edge >= N_EDGES) return;
    int lane = t & 31;
    int row = rows[edge]; int col = cols[edge]; float v = vals[edge];
    float4 xv = ((const float4*)(x + (size_t)col * D_FEAT))[lane];
    float* dst = agg + (size_t)row * D_FEAT + lane * 4;
    unsafeAtomicAdd(dst + 0, v * xv.x);
    unsafeAtomicAdd(dst + 1, v * xv.y);
    unsafeAtomicAdd(dst + 2, v * xv.z);
    unsafeAtomicAdd(dst + 3, v * xv.w);
    if (lane == 0) unsafeAtomicAdd(deg + row, v);
}

__global__ __launch_bounds__(256) void finalize_kernel(
    float* __restrict__ out, const float* __restrict__ deg, const float* __restrict__ bias)
{
    int t = blockIdx.x * blockDim.x + threadIdx.x;
    int node = t >> 5;
    if (node >= N_NODES) return;
    int lane = t & 31;
    float d = deg[node];
    float inv = (d == 0.f) ? 0.f : 1.f / d;
    float4* o = (float4*)(out + (size_t)node * D_FEAT) + lane;
    float4 bv = ((const float4*)bias)[lane];
    float4 ov = *o;
    ov.x = ov.x * inv + bv.x; ov.y = ov.y * inv + bv.y;
    ov.z = ov.z * inv + bv.z; ov.w = ov.w * inv + bv.w;
    *o = ov;
}

// ================= launch =================

extern "C" void kernel_launch(void* const* d_in, const int* in_sizes, int n_in,
                              void* d_out, int out_size, void* d_ws, size_t ws_size,
                              hipStream_t stream) {
    const float* x    = (const float*)d_in[0];
    const int*   rows = (const int*)  d_in[1];
    const int*   cols = (const int*)  d_in[2];
    const float* vals = (const float*)d_in[3];
    const float* bias = (const float*)d_in[4];
    float* out = (float*)d_out;

    // Fast-path layout (bytes):
    //   cursors  @ 0          ((N_NODES+1)*4 = 160,004; ocount = cursors[N_NODES])
    //   overflow @ 160,128    (OCAP * 8 = 65,536)
    //   x_bf     @ 225,792    (N_NODES*D_FEAT*2 = 10,240,000)
    //   bucket   @ 10,465,792 (N_NODES*CAP*4 = 5,120,000)  [128B aligned]
    char* wb = (char*)d_ws;
    int*      f_cursors  = (int*)     wb;
    int2*     f_overflow = (int2*)   (wb + 160128);
    uint2*    f_xbf      = (uint2*)  (wb + 225792);
    unsigned* f_bucket   = (unsigned*)(wb + 10465792);
    size_t need_fast = 10465792 + (size_t)N_NODES * CAP * 4;   // ~15.6 MB

    // CSR-path layout (ints): counts | offsets@40064 | cursors@80128 | blocksums@120128 | bucket@120448
    int* w = (int*)d_ws;
    size_t need_csr = ((size_t)120448 + 2u * N_EDGES) * sizeof(int);   // ~5.6 MB

    if (ws_size >= need_fast) {
        (void)hipMemsetAsync(f_cursors, 0, (size_t)(N_NODES + 1) * 4, stream);
        prep_kernel<<<SCAT_BLOCKS + CONV_BLOCKS, 256, 0, stream>>>(
            x, rows, cols, vals, f_cursors, f_bucket, f_overflow, f_xbf);
        gather_bf_kernel<<<N_NODES / 8, 256, 0, stream>>>(
            f_xbf, f_cursors, f_bucket, f_overflow, bias, out);
    } else if (ws_size >= need_csr) {
        int*  counts    = w;
        int*  offsets   = w + 40064;
        int*  cursors   = w + 80128;
        int*  blocksums = w + 120128;
        int2* bucket    = (int2*)(w + 120448);
        (void)hipMemsetAsync(counts, 0, N_NODES * sizeof(int), stream);
        histogram_kernel<<<(N_EDGES + 255) / 256, 256, 0, stream>>>(rows, counts);
        scan1_kernel<<<N_SCAN_BLOCKS, SCAN_BLOCK, 0, stream>>>(counts, offsets, blocksums);
        scan2_kernel<<<1, SCAN_BLOCK, 0, stream>>>(blocksums);
        scan3_kernel<<<N_SCAN_BLOCKS, SCAN_BLOCK, 0, stream>>>(offsets, cursors, blocksums);
        bucket_kernel<<<(N_EDGES + 255) / 256, 256, 0, stream>>>(rows, cols, vals, cursors, bucket);
        int threads = N_NODES * 32;
        gather_csr_kernel<<<(threads + 255) / 256, 256, 0, stream>>>(x, offsets, bucket, bias, out);
    } else {
        float* deg = (float*)d_ws;
        (void)hipMemsetAsync(out, 0, (size_t)N_NODES * D_FEAT * sizeof(float), stream);
        (void)hipMemsetAsync(deg, 0, (size_t)N_NODES * sizeof(float), stream);
        int et = N_EDGES * 32;
        edge_scatter_kernel<<<(et + 255) / 256, 256, 0, stream>>>(x, rows, cols, vals, out, deg);
        int nt = N_NODES * 32;
        finalize_kernel<<<(nt + 255) / 256, 256, 0, stream>>>(out, deg, bias);
    }
}